// Round 2
// baseline (524.191 us; speedup 1.0000x reference)
//
#include <hip/hip_runtime.h>
#include <math.h>

#define S_ 64
#define E_ 2048
#define H_ 32
#define D_ 64
#define L_ 2048
#define BS_ 16
#define BPS_ 128
#define QKV_N (3 * E_)   // 6144

// ---------------------------------------------------------------------------
// Tall-skinny GEMM: C[64,N] += A[64,K] @ B[K,N] (+ bias added by k-chunk 0).
// grid = (N/256, KSPLIT); block = 256. Thread: 4 consecutive cols x 16 rows.
// A tile in LDS, read as wave-uniform ds_read_b128 broadcast (conflict-free).
// LDS:FMA = 1:16 per instruction -> FMA-bound. C zeroed before launch.
// ---------------------------------------------------------------------------
__global__ __launch_bounds__(256) void gemm64(const float* __restrict__ A,
                                              const float* __restrict__ B,
                                              const float* __restrict__ bias,
                                              float* __restrict__ C,
                                              int K, int N) {
    __shared__ float As[64][32];
    const int t   = threadIdx.x;
    const int cg  = t & 63;                 // column group
    const int mg  = t >> 6;                 // row group: rows mg*16..+15
    const int colbase = blockIdx.x * 256 + cg * 4;
    const int kchunk  = K / gridDim.y;
    const int ks      = blockIdx.y * kchunk;

    float4 acc[16];
    if (blockIdx.y == 0) {
        float4 bb = *(const float4*)(bias + colbase);
#pragma unroll
        for (int mm = 0; mm < 16; ++mm) acc[mm] = bb;
    } else {
#pragma unroll
        for (int mm = 0; mm < 16; ++mm) acc[mm] = make_float4(0.f, 0.f, 0.f, 0.f);
    }

    for (int k0 = ks; k0 < ks + kchunk; k0 += 32) {
        __syncthreads();
#pragma unroll
        for (int i = 0; i < 2; ++i) {       // 512 float4 = 64 rows x 32 cols
            int f4  = t + i * 256;
            int row = f4 >> 3, c4 = f4 & 7;
            *(float4*)&As[row][c4 * 4] =
                *(const float4*)(A + (size_t)row * K + k0 + c4 * 4);
        }
        __syncthreads();
#pragma unroll
        for (int kk = 0; kk < 32; kk += 4) {
            float4 b0 = *(const float4*)(B + (size_t)(k0 + kk + 0) * N + colbase);
            float4 b1 = *(const float4*)(B + (size_t)(k0 + kk + 1) * N + colbase);
            float4 b2 = *(const float4*)(B + (size_t)(k0 + kk + 2) * N + colbase);
            float4 b3 = *(const float4*)(B + (size_t)(k0 + kk + 3) * N + colbase);
#pragma unroll
            for (int mm = 0; mm < 16; ++mm) {
                float4 a = *(const float4*)&As[mg * 16 + mm][kk];
                acc[mm].x = fmaf(a.x, b0.x, acc[mm].x);
                acc[mm].y = fmaf(a.x, b0.y, acc[mm].y);
                acc[mm].z = fmaf(a.x, b0.z, acc[mm].z);
                acc[mm].w = fmaf(a.x, b0.w, acc[mm].w);
                acc[mm].x = fmaf(a.y, b1.x, acc[mm].x);
                acc[mm].y = fmaf(a.y, b1.y, acc[mm].y);
                acc[mm].z = fmaf(a.y, b1.z, acc[mm].z);
                acc[mm].w = fmaf(a.y, b1.w, acc[mm].w);
                acc[mm].x = fmaf(a.z, b2.x, acc[mm].x);
                acc[mm].y = fmaf(a.z, b2.y, acc[mm].y);
                acc[mm].z = fmaf(a.z, b2.z, acc[mm].z);
                acc[mm].w = fmaf(a.z, b2.w, acc[mm].w);
                acc[mm].x = fmaf(a.w, b3.x, acc[mm].x);
                acc[mm].y = fmaf(a.w, b3.y, acc[mm].y);
                acc[mm].z = fmaf(a.w, b3.z, acc[mm].z);
                acc[mm].w = fmaf(a.w, b3.w, acc[mm].w);
            }
        }
    }
#pragma unroll
    for (int mm = 0; mm < 16; ++mm) {
        float* cp = C + (size_t)(mg * 16 + mm) * N + colbase;
        atomicAdd(cp + 0, acc[mm].x);
        atomicAdd(cp + 1, acc[mm].y);
        atomicAdd(cp + 2, acc[mm].z);
        atomicAdd(cp + 3, acc[mm].w);
    }
}

// ---------------------------------------------------------------------------
// Paged decode attention. One block per (seq, head); 4 waves per block.
// Lane = g*4+j: g = token slot (0..15) within a cache block, j = quarter of
// head_dim. Per-token-group online softmax (no cross-group shuffles in the
// loop) + double-buffered K/V prefetch (next block's 512 B in flight during
// compute). End: 4-round flash-merge butterfly over g, then LDS wave merge.
// ---------------------------------------------------------------------------
__global__ __launch_bounds__(256, 4) void paged_attn(
        const float* __restrict__ qkv,
        const float* __restrict__ kcache,
        const float* __restrict__ vcache,
        const int* __restrict__ btab,
        const int* __restrict__ clens,
        float* __restrict__ attn) {
    const int bid  = blockIdx.x;
    const int s    = bid >> 5;
    const int h    = bid & 31;
    const int t    = threadIdx.x;
    const int w    = t >> 6;
    const int lane = t & 63;
    const int g    = lane >> 2;
    const int j    = lane & 3;
    const int ctx  = clens[s];
    const int nb   = (ctx + 15) >> 4;   // >= 64 since ctx >= 1024
    const float scale = 0.125f;

    const float* qp = qkv + (size_t)s * QKV_N + h * 64 + j * 4;
    float4 q4[4];
#pragma unroll
    for (int i = 0; i < 4; ++i) q4[i] = *(const float4*)(qp + i * 16);

    float m = -1e30f, l = 0.f;
    float4 acc[4];
#pragma unroll
    for (int i = 0; i < 4; ++i) acc[i] = make_float4(0.f, 0.f, 0.f, 0.f);

    const int* bt = btab + s * BPS_;
    const int hoff = h * 64 + j * 4;

    auto LOAD = [&](float4* kr, float4* vr, int b) {
        const int blk = bt[b];
        const size_t base = ((size_t)blk * BS_ + g) * (H_ * D_) + hoff;
        const float* kp = kcache + base;
        const float* vp = vcache + base;
#pragma unroll
        for (int i = 0; i < 4; ++i) kr[i] = *(const float4*)(kp + i * 16);
#pragma unroll
        for (int i = 0; i < 4; ++i) vr[i] = *(const float4*)(vp + i * 16);
    };
    auto STEP = [&](const float4* kr, const float4* vr, int b) {
        float part = 0.f;
#pragma unroll
        for (int i = 0; i < 4; ++i)
            part += q4[i].x * kr[i].x + q4[i].y * kr[i].y +
                    q4[i].z * kr[i].z + q4[i].w * kr[i].w;
        part += __shfl_xor(part, 1);
        part += __shfl_xor(part, 2);
        const int tok = b * 16 + g;
        float score = (tok < ctx) ? part * scale : -1e38f;
        float nm = fmaxf(m, score);
        float r  = __expf(m - nm);
        float p  = __expf(score - nm);
        m = nm;
        l = fmaf(l, r, p);
#pragma unroll
        for (int i = 0; i < 4; ++i) {
            acc[i].x = fmaf(p, vr[i].x, acc[i].x * r);
            acc[i].y = fmaf(p, vr[i].y, acc[i].y * r);
            acc[i].z = fmaf(p, vr[i].z, acc[i].z * r);
            acc[i].w = fmaf(p, vr[i].w, acc[i].w * r);
        }
    };

    float4 kA[4], vA[4], kB[4], vB[4];
    int b = w;
    LOAD(kA, vA, b);
    while (true) {
        const int b1 = b + 4;
        const bool m1 = b1 < nb;
        if (m1) LOAD(kB, vB, b1);
        STEP(kA, vA, b);
        if (!m1) break;
        const int b2 = b1 + 4;
        const bool m2 = b2 < nb;
        if (m2) LOAD(kA, vA, b2);
        STEP(kB, vB, b1);
        if (!m2) break;
        b = b2;
    }

    // flash-merge the 16 token-groups (lane bits 2..5) within the wave
#pragma unroll
    for (int msk = 4; msk <= 32; msk <<= 1) {
        float om = __shfl_xor(m, msk);
        float ol = __shfl_xor(l, msk);
        float nm = fmaxf(m, om);
        float ra = __expf(m - nm);
        float rb = __expf(om - nm);
        l = ra * l + rb * ol;
#pragma unroll
        for (int i = 0; i < 4; ++i) {
            acc[i].x = ra * acc[i].x + rb * __shfl_xor(acc[i].x, msk);
            acc[i].y = ra * acc[i].y + rb * __shfl_xor(acc[i].y, msk);
            acc[i].z = ra * acc[i].z + rb * __shfl_xor(acc[i].z, msk);
            acc[i].w = ra * acc[i].w + rb * __shfl_xor(acc[i].w, msk);
        }
        m = nm;
    }

    // current token (position L, always attended) -- folded into wave 0
    if (w == 0) {
        const float* kn = qkv + (size_t)s * QKV_N + E_ + h * 64 + j * 4;
        const float* vn = qkv + (size_t)s * QKV_N + 2 * E_ + h * 64 + j * 4;
        float4 k4[4];
#pragma unroll
        for (int i = 0; i < 4; ++i) k4[i] = *(const float4*)(kn + i * 16);
        float part = 0.f;
#pragma unroll
        for (int i = 0; i < 4; ++i)
            part += q4[i].x * k4[i].x + q4[i].y * k4[i].y +
                    q4[i].z * k4[i].z + q4[i].w * k4[i].w;
        part += __shfl_xor(part, 1);
        part += __shfl_xor(part, 2);
        float score = part * scale;     // uniform across all 64 lanes
        float nm = fmaxf(m, score);
        float r  = __expf(m - nm);
        float p  = __expf(score - nm);
        l = fmaf(l, r, p);
#pragma unroll
        for (int i = 0; i < 4; ++i) {
            float4 v4 = *(const float4*)(vn + i * 16);
            acc[i].x = fmaf(p, v4.x, acc[i].x * r);
            acc[i].y = fmaf(p, v4.y, acc[i].y * r);
            acc[i].z = fmaf(p, v4.z, acc[i].z * r);
            acc[i].w = fmaf(p, v4.w, acc[i].w * r);
        }
        m = nm;
    }

    // merge the 4 waves via LDS
    __shared__ float lm[4], ll[4], la[4][64];
    if (g == 0) {                       // lanes 0..3 hold the wave's 64 dims
#pragma unroll
        for (int i = 0; i < 4; ++i) {
            la[w][i * 16 + j * 4 + 0] = acc[i].x;
            la[w][i * 16 + j * 4 + 1] = acc[i].y;
            la[w][i * 16 + j * 4 + 2] = acc[i].z;
            la[w][i * 16 + j * 4 + 3] = acc[i].w;
        }
    }
    if (lane == 0) { lm[w] = m; ll[w] = l; }
    __syncthreads();

    if (t < 64) {
        const int d = t;
        float M = fmaxf(fmaxf(lm[0], lm[1]), fmaxf(lm[2], lm[3]));
        float Lsum = 0.f, o = 0.f;
#pragma unroll
        for (int ww = 0; ww < 4; ++ww) {
            float f = __expf(lm[ww] - M);
            Lsum += f * ll[ww];
            o += f * la[ww][d];
        }
        attn[(size_t)s * E_ + h * 64 + d] = o / Lsum;
    }
}

// ---------------------------------------------------------------------------
extern "C" void kernel_launch(void* const* d_in, const int* in_sizes, int n_in,
                              void* d_out, int out_size, void* d_ws, size_t ws_size,
                              hipStream_t stream) {
    const float* hidden = (const float*)d_in[0];
    const float* wqkv   = (const float*)d_in[1];
    const float* bqkv   = (const float*)d_in[2];
    const float* wout   = (const float*)d_in[3];
    const float* bout   = (const float*)d_in[4];
    const float* kcache = (const float*)d_in[5];
    const float* vcache = (const float*)d_in[6];
    const int*   btab   = (const int*)d_in[7];
    const int*   clens  = (const int*)d_in[8];
    float* out = (float*)d_out;

    float* qkv     = (float*)d_ws;                    // [64, 6144]
    float* attnbuf = qkv + (size_t)S_ * QKV_N;        // [64, 2048]

    hipMemsetAsync(qkv, 0, (size_t)S_ * QKV_N * sizeof(float), stream);
    hipMemsetAsync(out, 0, (size_t)S_ * E_ * sizeof(float), stream);

    // 1) fused QKV projection: [64,2048] x [2048,6144] + bias
    gemm64<<<dim3(QKV_N / 256, 16), 256, 0, stream>>>(hidden, wqkv, bqkv, qkv,
                                                      E_, QKV_N);
    // 2) paged attention -> attnbuf [64, 2048]
    paged_attn<<<dim3(S_ * H_), 256, 0, stream>>>(qkv, kcache, vcache, btab,
                                                  clens, attnbuf);
    // 3) output projection: [64,2048] x [2048,2048] + bias -> d_out
    gemm64<<<dim3(E_ / 256, 32), 256, 0, stream>>>(attnbuf, wout, bout, out,
                                                   E_, E_);
}

// Round 3
// 405.291 us; speedup vs baseline: 1.2934x; 1.2934x over previous
//
#include <hip/hip_runtime.h>
#include <math.h>

#define S_ 64
#define E_ 2048
#define H_ 32
#define D_ 64
#define L_ 2048
#define BS_ 16
#define BPS_ 128
#define QKV_N (3 * E_)   // 6144

// ---------------------------------------------------------------------------
// Tall-skinny GEMM: C[64,N] += A[64,K] @ B[K,N] (+ bias added by k-chunk 0).
// grid = (N/128, KSPLIT); block = 256. Thread: 2 consecutive cols x 16 rows.
// A tile in LDS, read as wave-uniform ds_read_b128 broadcast (1 DS op per
// 8 FMAs -> FMA-bound). C must be zeroed before launch (atomicAdd across
// k-chunks, bias folded into chunk 0).
// ---------------------------------------------------------------------------
__global__ __launch_bounds__(256) void gemm64(const float* __restrict__ A,
                                              const float* __restrict__ B,
                                              const float* __restrict__ bias,
                                              float* __restrict__ C,
                                              int K, int N) {
    __shared__ float As[64][32];
    const int t    = threadIdx.x;
    const int lane = t & 63;
    const int mg   = t >> 6;                // wave id = row group (16 rows)
    const int colbase = blockIdx.x * 128 + lane * 2;
    const int kchunk  = K / gridDim.y;
    const int ks      = blockIdx.y * kchunk;

    float2 acc[16];
    if (blockIdx.y == 0) {
        float2 bb = *(const float2*)(bias + colbase);
#pragma unroll
        for (int mm = 0; mm < 16; ++mm) acc[mm] = bb;
    } else {
#pragma unroll
        for (int mm = 0; mm < 16; ++mm) acc[mm] = make_float2(0.f, 0.f);
    }

    for (int k0 = ks; k0 < ks + kchunk; k0 += 32) {
        __syncthreads();
#pragma unroll
        for (int i = 0; i < 2; ++i) {       // 512 float4 = 64 rows x 32 k
            int f4  = t + i * 256;
            int row = f4 >> 3, c4 = f4 & 7;
            *(float4*)&As[row][c4 * 4] =
                *(const float4*)(A + (size_t)row * K + k0 + c4 * 4);
        }
        __syncthreads();
#pragma unroll
        for (int kk = 0; kk < 32; kk += 4) {
            float2 b0 = *(const float2*)(B + (size_t)(k0 + kk + 0) * N + colbase);
            float2 b1 = *(const float2*)(B + (size_t)(k0 + kk + 1) * N + colbase);
            float2 b2 = *(const float2*)(B + (size_t)(k0 + kk + 2) * N + colbase);
            float2 b3 = *(const float2*)(B + (size_t)(k0 + kk + 3) * N + colbase);
#pragma unroll
            for (int mm = 0; mm < 16; ++mm) {
                float4 a = *(const float4*)&As[mg * 16 + mm][kk];
                acc[mm].x = fmaf(a.x, b0.x, acc[mm].x);
                acc[mm].y = fmaf(a.x, b0.y, acc[mm].y);
                acc[mm].x = fmaf(a.y, b1.x, acc[mm].x);
                acc[mm].y = fmaf(a.y, b1.y, acc[mm].y);
                acc[mm].x = fmaf(a.z, b2.x, acc[mm].x);
                acc[mm].y = fmaf(a.z, b2.y, acc[mm].y);
                acc[mm].x = fmaf(a.w, b3.x, acc[mm].x);
                acc[mm].y = fmaf(a.w, b3.y, acc[mm].y);
            }
        }
    }
#pragma unroll
    for (int mm = 0; mm < 16; ++mm) {
        float* cp = C + (size_t)(mg * 16 + mm) * N + colbase;
        atomicAdd(cp + 0, acc[mm].x);
        atomicAdd(cp + 1, acc[mm].y);
    }
}

// ---------------------------------------------------------------------------
// Paged decode attention. One block per (seq, head); 4 waves, K-split by 4.
// Lane = g*8+j: g = token sub-slot (0..7), j = eighth of head_dim. A cache
// block (16 tokens) is two half-steps of 8 tokens. Per-lane state: 8 floats
// each of q/k/v/acc -> ~55 VGPR -> 6+ waves/SIMD (launch_bounds(256,6)).
// Per-token-group online softmax (only 3 intra-group shuffles per token in
// the loop). End: flash-merge over the 8 groups (xor 8/16/32), new-token
// step on wave 0, then LDS merge of 4 waves.
// ---------------------------------------------------------------------------
__global__ __launch_bounds__(256, 6) void paged_attn(
        const float* __restrict__ qkv,
        const float* __restrict__ kcache,
        const float* __restrict__ vcache,
        const int* __restrict__ btab,
        const int* __restrict__ clens,
        float* __restrict__ attn) {
    const int bid  = blockIdx.x;
    const int s    = bid >> 5;
    const int h    = bid & 31;
    const int t    = threadIdx.x;
    const int w    = t >> 6;
    const int lane = t & 63;
    const int g    = lane >> 3;         // token sub-slot
    const int j    = lane & 7;          // eighth of head_dim
    const int ctx  = clens[s];
    const int nb   = (ctx + 15) >> 4;   // >= 64 since ctx >= 1024
    const float scale = 0.125f;

    const float* qp = qkv + (size_t)s * QKV_N + h * 64 + j * 8;
    const float4 q0 = *(const float4*)(qp);
    const float4 q1 = *(const float4*)(qp + 4);

    float m = -1e30f, l = 0.f;
    float4 a0 = make_float4(0.f, 0.f, 0.f, 0.f);
    float4 a1 = make_float4(0.f, 0.f, 0.f, 0.f);

    const int* bt   = btab + s * BPS_;
    const int  hoff = h * 64 + j * 8;

    for (int b = w; b < nb; b += 4) {
        const int blk = bt[b];
        const size_t blkbase = (size_t)blk * (BS_ * H_ * D_) + hoff;
#pragma unroll
        for (int half = 0; half < 2; ++half) {
            const size_t base = blkbase + (size_t)(half * 8 + g) * (H_ * D_);
            const float* kp = kcache + base;
            const float* vp = vcache + base;
            const float4 k0 = *(const float4*)(kp);
            const float4 k1 = *(const float4*)(kp + 4);
            const float4 v0 = *(const float4*)(vp);
            const float4 v1 = *(const float4*)(vp + 4);

            float part = q0.x * k0.x + q0.y * k0.y + q0.z * k0.z + q0.w * k0.w
                       + q1.x * k1.x + q1.y * k1.y + q1.z * k1.z + q1.w * k1.w;
            part += __shfl_xor(part, 1);
            part += __shfl_xor(part, 2);
            part += __shfl_xor(part, 4);

            const int tok = b * 16 + half * 8 + g;
            const float score = (tok < ctx) ? part * scale : -1e38f;
            const float nm = fmaxf(m, score);
            const float r  = __expf(m - nm);
            const float p  = __expf(score - nm);
            m = nm;
            l = fmaf(l, r, p);
            a0.x = fmaf(p, v0.x, a0.x * r);
            a0.y = fmaf(p, v0.y, a0.y * r);
            a0.z = fmaf(p, v0.z, a0.z * r);
            a0.w = fmaf(p, v0.w, a0.w * r);
            a1.x = fmaf(p, v1.x, a1.x * r);
            a1.y = fmaf(p, v1.y, a1.y * r);
            a1.z = fmaf(p, v1.z, a1.z * r);
            a1.w = fmaf(p, v1.w, a1.w * r);
        }
    }

    // flash-merge the 8 token-groups (lane bits 3..5)
#pragma unroll
    for (int msk = 8; msk <= 32; msk <<= 1) {
        float om = __shfl_xor(m, msk);
        float ol = __shfl_xor(l, msk);
        float nm = fmaxf(m, om);
        float ra = __expf(m - nm);
        float rb = __expf(om - nm);
        l = ra * l + rb * ol;
        a0.x = ra * a0.x + rb * __shfl_xor(a0.x, msk);
        a0.y = ra * a0.y + rb * __shfl_xor(a0.y, msk);
        a0.z = ra * a0.z + rb * __shfl_xor(a0.z, msk);
        a0.w = ra * a0.w + rb * __shfl_xor(a0.w, msk);
        a1.x = ra * a1.x + rb * __shfl_xor(a1.x, msk);
        a1.y = ra * a1.y + rb * __shfl_xor(a1.y, msk);
        a1.z = ra * a1.z + rb * __shfl_xor(a1.z, msk);
        a1.w = ra * a1.w + rb * __shfl_xor(a1.w, msk);
        m = nm;
    }

    // current token (position L, always attended) -- wave 0, all lanes
    if (w == 0) {
        const float* kn = qkv + (size_t)s * QKV_N + E_ + h * 64 + j * 8;
        const float* vn = qkv + (size_t)s * QKV_N + 2 * E_ + h * 64 + j * 8;
        const float4 k0 = *(const float4*)(kn);
        const float4 k1 = *(const float4*)(kn + 4);
        float part = q0.x * k0.x + q0.y * k0.y + q0.z * k0.z + q0.w * k0.w
                   + q1.x * k1.x + q1.y * k1.y + q1.z * k1.z + q1.w * k1.w;
        part += __shfl_xor(part, 1);
        part += __shfl_xor(part, 2);
        part += __shfl_xor(part, 4);
        const float score = part * scale;   // uniform across the wave
        const float nm = fmaxf(m, score);
        const float r  = __expf(m - nm);
        const float p  = __expf(score - nm);
        l = fmaf(l, r, p);
        const float4 v0 = *(const float4*)(vn);
        const float4 v1 = *(const float4*)(vn + 4);
        a0.x = fmaf(p, v0.x, a0.x * r);
        a0.y = fmaf(p, v0.y, a0.y * r);
        a0.z = fmaf(p, v0.z, a0.z * r);
        a0.w = fmaf(p, v0.w, a0.w * r);
        a1.x = fmaf(p, v1.x, a1.x * r);
        a1.y = fmaf(p, v1.y, a1.y * r);
        a1.z = fmaf(p, v1.z, a1.z * r);
        a1.w = fmaf(p, v1.w, a1.w * r);
        m = nm;
    }

    // merge the 4 waves via LDS
    __shared__ float lm[4], ll[4], la[4][64];
    if (g == 0) {                       // lanes 0..7 hold the wave's 64 dims
        *(float4*)&la[w][j * 8]     = a0;
        *(float4*)&la[w][j * 8 + 4] = a1;
    }
    if (lane == 0) { lm[w] = m; ll[w] = l; }
    __syncthreads();

    if (t < 64) {
        const int d = t;
        float M = fmaxf(fmaxf(lm[0], lm[1]), fmaxf(lm[2], lm[3]));
        float Lsum = 0.f, o = 0.f;
#pragma unroll
        for (int ww = 0; ww < 4; ++ww) {
            float f = __expf(lm[ww] - M);
            Lsum += f * ll[ww];
            o += f * la[ww][d];
        }
        attn[(size_t)s * E_ + h * 64 + d] = o / Lsum;
    }
}

// ---------------------------------------------------------------------------
extern "C" void kernel_launch(void* const* d_in, const int* in_sizes, int n_in,
                              void* d_out, int out_size, void* d_ws, size_t ws_size,
                              hipStream_t stream) {
    const float* hidden = (const float*)d_in[0];
    const float* wqkv   = (const float*)d_in[1];
    const float* bqkv   = (const float*)d_in[2];
    const float* wout   = (const float*)d_in[3];
    const float* bout   = (const float*)d_in[4];
    const float* kcache = (const float*)d_in[5];
    const float* vcache = (const float*)d_in[6];
    const int*   btab   = (const int*)d_in[7];
    const int*   clens  = (const int*)d_in[8];
    float* out = (float*)d_out;

    float* qkv     = (float*)d_ws;                    // [64, 6144]
    float* attnbuf = qkv + (size_t)S_ * QKV_N;        // [64, 2048]

    hipMemsetAsync(qkv, 0, (size_t)S_ * QKV_N * sizeof(float), stream);
    hipMemsetAsync(out, 0, (size_t)S_ * E_ * sizeof(float), stream);

    // 1) fused QKV projection: [64,2048] x [2048,6144] + bias
    gemm64<<<dim3(QKV_N / 128, 8), 256, 0, stream>>>(hidden, wqkv, bqkv, qkv,
                                                     E_, QKV_N);
    // 2) paged attention -> attnbuf [64, 2048]
    paged_attn<<<dim3(S_ * H_), 256, 0, stream>>>(qkv, kcache, vcache, btab,
                                                  clens, attnbuf);
    // 3) output projection: [64,2048] x [2048,2048] + bias -> d_out
    gemm64<<<dim3(E_ / 128, 16), 256, 0, stream>>>(attnbuf, wout, bout, out,
                                                   E_, E_);
}